// Round 9
// baseline (332.477 us; speedup 1.0000x reference)
//
#include <hip/hip_runtime.h>
#include <math.h>

// Problem constants (match reference)
#define BB    16
#define NSRC  1024
#define NDST  4096
#define CIN   256
#define CSKIP 128
#define CHID  256
#define NROWS (BB * NDST)   // 65536 output rows
#define K1    (CIN + CSKIP) // 384
#define K2    CHID          // 256

typedef __attribute__((ext_vector_type(8))) short bf16x8;   // 8 bf16 (4 VGPRs)
typedef __attribute__((ext_vector_type(4))) float f32x4;    // MFMA accum

// round-to-nearest-even f32 -> bf16
__device__ inline unsigned short f2bf(float f) {
    union { float f; unsigned u; } v; v.f = f;
    unsigned r = v.u + 0x7FFFu + ((v.u >> 16) & 1u);
    return (unsigned short)(r >> 16);
}

// Exact merge of two sorted (d,idx) triples -> top-3, lex order (d, then idx).
// Mutates the first triple. Matches jax.lax.top_k tie semantics.
__device__ inline void merge3(float& a0, int& x0, float& a1, int& x1, float& a2, int& x2,
                              float b0, int y0, float b1, int y1, float b2, int y2)
{
    const bool t0 = (a0 < b0) || (a0 == b0 && x0 < y0);
    const float r0 = t0 ? a0 : b0; const int s0 = t0 ? x0 : y0;
    const float A0 = t0 ? a1 : a0; const int X0 = t0 ? x1 : x0;
    const float A1 = t0 ? a2 : a1; const int X1 = t0 ? x2 : x1;
    const float B0 = t0 ? b0 : b1; const int Y0 = t0 ? y0 : y1;
    const float B1 = t0 ? b1 : b2; const int Y1 = t0 ? y1 : y2;
    const bool t1 = (A0 < B0) || (A0 == B0 && X0 < Y0);
    const float r1 = t1 ? A0 : B0; const int s1 = t1 ? X0 : Y0;
    const float A0b = t1 ? A1 : A0; const int X0b = t1 ? X1 : X0;
    const float B0b = t1 ? B0 : B1; const int Y0b = t1 ? Y0 : Y1;
    const bool t2 = (A0b < B0b) || (A0b == B0b && X0b < Y0b);
    a0 = r0; x0 = s0;
    a1 = r1; x1 = s1;
    a2 = t2 ? A0b : B0b; x2 = t2 ? X0b : Y0b;
}

// ---------------------------------------------------------------------------
// Kernel 1: 3-NN. R8 counters: 111us, VALUBusy 22%, Occ 11% -> latency-bound
// on the serial sorted-insert chain. Fix: 4 independent chains (ILP x4),
// exact lex merge at the end.
// ---------------------------------------------------------------------------
__global__ __launch_bounds__(256) void knn_kernel(
    const float* __restrict__ pos,       // [BB*NSRC, 3]
    const float* __restrict__ pos_skip,  // [BB*NDST, 3]
    int*   __restrict__ nidx,            // [BB*NDST, 3]
    float* __restrict__ nw)              // [BB*NDST, 3]
{
    __shared__ float4 sp[NSRC];          // 16 KB
    const int bpc = NDST / 256;          // 16 blocks per cloud
    const int b   = blockIdx.x / bpc;
    const int r0  = (blockIdx.x % bpc) * 256;
    const int tid = threadIdx.x;

    const float* ps = pos + (size_t)b * NSRC * 3;
    for (int i = tid; i < NSRC; i += 256)
        sp[i] = make_float4(ps[i * 3 + 0], ps[i * 3 + 1], ps[i * 3 + 2], 0.f);
    __syncthreads();

    const int dr = b * NDST + r0 + tid;
    const float qx = pos_skip[dr * 3 + 0];
    const float qy = pos_skip[dr * 3 + 1];
    const float qz = pos_skip[dr * 3 + 2];

    // 4 independent top-3 chains over j = c, c+4, c+8, ... (c = 0..3)
    float cb0[4], cb1[4], cb2[4];
    int   ci0[4], ci1[4], ci2[4];
#pragma unroll
    for (int c = 0; c < 4; ++c) {
        cb0[c] = cb1[c] = cb2[c] = 3.4e38f;
        ci0[c] = ci1[c] = ci2[c] = 0x7fffffff;
    }
#pragma unroll 2
    for (int j = 0; j < NSRC; j += 4) {
#pragma unroll
        for (int c = 0; c < 4; ++c) {
            const float4 p = sp[j + c];
            const float dx = qx - p.x, dy = qy - p.y, dz = qz - p.z;
            const float d  = dx * dx + dy * dy + dz * dz;
            if (d < cb2[c]) {            // strict <: earliest index wins in-chain
                if (d < cb0[c])      { cb2[c]=cb1[c]; ci2[c]=ci1[c]; cb1[c]=cb0[c]; ci1[c]=ci0[c]; cb0[c]=d; ci0[c]=j+c; }
                else if (d < cb1[c]) { cb2[c]=cb1[c]; ci2[c]=ci1[c]; cb1[c]=d; ci1[c]=j+c; }
                else                 { cb2[c]=d; ci2[c]=j+c; }
            }
        }
    }
    // merge chains: (0,1) -> 0, (2,3) -> 2, (0,2) -> 0   (lex-exact)
    merge3(cb0[0],ci0[0],cb1[0],ci1[0],cb2[0],ci2[0], cb0[1],ci0[1],cb1[1],ci1[1],cb2[1],ci2[1]);
    merge3(cb0[2],ci0[2],cb1[2],ci1[2],cb2[2],ci2[2], cb0[3],ci0[3],cb1[3],ci1[3],cb2[3],ci2[3]);
    merge3(cb0[0],ci0[0],cb1[0],ci1[0],cb2[0],ci2[0], cb0[2],ci0[2],cb1[2],ci1[2],cb2[2],ci2[2]);

    const float w0 = 1.0f / (cb0[0] + 1e-16f);
    const float w1 = 1.0f / (cb1[0] + 1e-16f);
    const float w2 = 1.0f / (cb2[0] + 1e-16f);
    const float inv = 1.0f / (w0 + w1 + w2);

    nidx[dr * 3 + 0] = b * NSRC + ci0[0];
    nidx[dr * 3 + 1] = b * NSRC + ci1[0];
    nidx[dr * 3 + 2] = b * NSRC + ci2[0];
    nw[dr * 3 + 0] = w0 * inv;
    nw[dr * 3 + 1] = w1 * inv;
    nw[dr * 3 + 2] = w2 * inv;
}

// ---------------------------------------------------------------------------
// Kernel 2: one-shot W transpose + bf16 cast: Wt[n][k] = bf16(W[k][n]).
// ---------------------------------------------------------------------------
__global__ __launch_bounds__(256) void wt_kernel(
    const float* __restrict__ W1, const float* __restrict__ W2,
    unsigned short* __restrict__ W1t, unsigned short* __restrict__ W2t)
{
    const int id = blockIdx.x * 256 + threadIdx.x;
    if (id < 256 * K1) {
        const int n = id / K1, k = id % K1;
        W1t[id] = f2bf(W1[(size_t)k * 256 + n]);
    }
    if (id < 256 * K2) {
        const int n = id / K2, k = id % K2;
        W2t[id] = f2bf(W2[(size_t)k * 256 + n]);
    }
}

// ---------------------------------------------------------------------------
// Kernel 3/4: bf16 MFMA GEMM, 2-phase pipeline (T3-minimum):
//   double-buffered LDS, ONE barrier per K-step, next-tile loads issued
//   BEFORE the MFMA cluster (issue-early / write-late).
// BM=BN=128, BK=32, 256 threads (4 waves, 2x2), 4x4 16x16x32 frags, fp32 acc.
// interp indices/weights held in registers (each thread only uses row tid>>1)
// -> LDS = 2*2*128*40*2B = 40960 B exactly -> 4 blocks/CU.
// ---------------------------------------------------------------------------
template <int KDIM, bool FIRST>
__global__ __launch_bounds__(256) void mfma_gemm_kernel(
    const float* __restrict__ x,             // FIRST
    const float* __restrict__ x_skip,        // FIRST
    const unsigned short* __restrict__ hin,  // !FIRST
    const int*   __restrict__ nidx,          // FIRST
    const float* __restrict__ nw,            // FIRST
    const unsigned short* __restrict__ Wt,   // [256][KDIM] bf16 (B^T)
    const float* __restrict__ bias,          // [256]
    unsigned short* __restrict__ hout,       // FIRST
    float* __restrict__ fout)                // !FIRST
{
    constexpr int BM = 128, BN = 128, BK = 32, PAD = 40;
    __shared__ __align__(16) unsigned short At[2][BM][PAD];
    __shared__ __align__(16) unsigned short Bt[2][BN][PAD];

    const int tid  = threadIdx.x;
    const int mblk = blockIdx.x >> 1;
    const int nblk = blockIdx.x & 1;
    const int rowBase = mblk * BM;
    const int nbase   = nblk * BN;

    const int r  = tid >> 1;               // staging row (A and B tiles)
    const int kh = (tid & 1) * 16;         // staging k-offset

    // interp metadata in registers (row r only)
    int   gi0 = 0, gi1 = 0, gi2 = 0;
    float gw0 = 0.f, gw1 = 0.f, gw2 = 0.f;
    if (FIRST) {
        const size_t g = (size_t)(rowBase + r) * 3;
        gi0 = nidx[g + 0]; gi1 = nidx[g + 1]; gi2 = nidx[g + 2];
        gw0 = nw[g + 0];   gw1 = nw[g + 1];   gw2 = nw[g + 2];
    }

    f32x4 acc[4][4];
#pragma unroll
    for (int i = 0; i < 4; ++i)
#pragma unroll
        for (int j = 0; j < 4; ++j) acc[i][j] = (f32x4){0.f, 0.f, 0.f, 0.f};

    const int l  = tid & 63;
    const int w  = tid >> 6;
    const int wm = w >> 1, wn = w & 1;     // 2x2 wave grid
    const int cl = l & 15;                 // row/col within fragment
    const int k0 = (l >> 4) * 8;           // k-offset within fragment

    unsigned short a_s[16];
    bf16x8 b_s0, b_s1;

    auto stageA = [&](int kt) {
        if (FIRST) {
            const int c = kt + kh;
            if (kt < CIN) {                // interp gather (both kh land < CIN)
                const float4* x4 = (const float4*)x;
                const size_t g0 = (size_t)gi0 * (CIN / 4) + (c >> 2);
                const size_t g1 = (size_t)gi1 * (CIN / 4) + (c >> 2);
                const size_t g2 = (size_t)gi2 * (CIN / 4) + (c >> 2);
#pragma unroll
                for (int cc = 0; cc < 4; ++cc) {
                    const float4 f0 = x4[g0 + cc];
                    const float4 f1 = x4[g1 + cc];
                    const float4 f2 = x4[g2 + cc];
                    a_s[cc * 4 + 0] = f2bf(gw0 * f0.x + gw1 * f1.x + gw2 * f2.x);
                    a_s[cc * 4 + 1] = f2bf(gw0 * f0.y + gw1 * f1.y + gw2 * f2.y);
                    a_s[cc * 4 + 2] = f2bf(gw0 * f0.z + gw1 * f1.z + gw2 * f2.z);
                    a_s[cc * 4 + 3] = f2bf(gw0 * f0.w + gw1 * f1.w + gw2 * f2.w);
                }
            } else {                       // x_skip passthrough
                const float4* xs4 = (const float4*)x_skip;
                const size_t gs = (size_t)(rowBase + r) * (CSKIP / 4) + ((c - CIN) >> 2);
#pragma unroll
                for (int cc = 0; cc < 4; ++cc) {
                    const float4 f = xs4[gs + cc];
                    a_s[cc * 4 + 0] = f2bf(f.x);
                    a_s[cc * 4 + 1] = f2bf(f.y);
                    a_s[cc * 4 + 2] = f2bf(f.z);
                    a_s[cc * 4 + 3] = f2bf(f.w);
                }
            }
        } else {                           // A = h (already bf16)
            const unsigned short* hp = &hin[(size_t)(rowBase + r) * K2 + kt + kh];
            *(bf16x8*)&a_s[0] = *(const bf16x8*)&hp[0];
            *(bf16x8*)&a_s[8] = *(const bf16x8*)&hp[8];
        }
    };
    auto stageB = [&](int kt) {
        const unsigned short* wp = &Wt[(size_t)(nbase + r) * KDIM + kt + kh];
        b_s0 = *(const bf16x8*)&wp[0];
        b_s1 = *(const bf16x8*)&wp[8];
    };

    stageA(0); stageB(0);                  // prologue

    int buf = 0;
    for (int kt = 0; kt < KDIM; kt += BK, buf ^= 1) {
        // write-late: staged regs -> LDS[buf]
        *(bf16x8*)&At[buf][r][kh]     = *(bf16x8*)&a_s[0];
        *(bf16x8*)&At[buf][r][kh + 8] = *(bf16x8*)&a_s[8];
        *(bf16x8*)&Bt[buf][r][kh]     = b_s0;
        *(bf16x8*)&Bt[buf][r][kh + 8] = b_s1;
        __syncthreads();                   // tile[buf] ready (single barrier/step;
                                           // concurrent writes of step t+1 hit buf^1)
        // issue-early: next tile's global loads overlap the MFMA cluster below
        if (kt + BK < KDIM) { stageA(kt + BK); stageB(kt + BK); }

        bf16x8 af[4], bfr[4];
#pragma unroll
        for (int mt = 0; mt < 4; ++mt)
            af[mt] = *(const bf16x8*)&At[buf][wm * 64 + mt * 16 + cl][k0];
#pragma unroll
        for (int nt = 0; nt < 4; ++nt)
            bfr[nt] = *(const bf16x8*)&Bt[buf][wn * 64 + nt * 16 + cl][k0];
#pragma unroll
        for (int mt = 0; mt < 4; ++mt)
#pragma unroll
            for (int nt = 0; nt < 4; ++nt)
                acc[mt][nt] = __builtin_amdgcn_mfma_f32_16x16x32_bf16(
                    af[mt], bfr[nt], acc[mt][nt], 0, 0, 0);
    }

    // ---- epilogue: D layout col = l&15, row = (l>>4)*4 + reg [m89] ----
    const int rg = (l >> 4) * 4;
#pragma unroll
    for (int nt = 0; nt < 4; ++nt) {
        const int col = nbase + wn * 64 + nt * 16 + cl;
        const float bv = bias[col];
#pragma unroll
        for (int mt = 0; mt < 4; ++mt) {
            const int row = rowBase + wm * 64 + mt * 16 + rg;
#pragma unroll
            for (int rr = 0; rr < 4; ++rr) {
                float v = acc[mt][nt][rr] + bv;
                if (FIRST) {
                    v = fmaxf(v, 0.f);
                    hout[(size_t)(row + rr) * CHID + col] = f2bf(v);
                } else {
                    fout[(size_t)(row + rr) * CHID + col] = v;
                }
            }
        }
    }
}

// ---------------------------------------------------------------------------
// Kernel 5: tuple tail (guarded by out_size).
// ---------------------------------------------------------------------------
__global__ __launch_bounds__(256) void tail_kernel(
    const float* __restrict__ pos_skip, float* __restrict__ out, int tailElems)
{
    const int i  = blockIdx.x * blockDim.x + threadIdx.x;
    const int PS = NROWS * 3;
    float* o1 = out + (size_t)NROWS * CHID;
    if (i < PS) o1[i] = pos_skip[i];
    if (i < NROWS) {
        const int bval = i >> 12;          // i / NDST
        if (tailElems == NROWS) {
            o1[PS + i] = (float)bval;
        } else if (tailElems == 2 * NROWS) {
            ((long long*)(o1 + PS))[i] = (long long)bval;
        }
    }
}

// ---------------------------------------------------------------------------
extern "C" void kernel_launch(void* const* d_in, const int* in_sizes, int n_in,
                              void* d_out, int out_size, void* d_ws, size_t ws_size,
                              hipStream_t stream)
{
    const float* x        = (const float*)d_in[0];
    const float* pos      = (const float*)d_in[1];
    const float* x_skip   = (const float*)d_in[3];
    const float* pos_skip = (const float*)d_in[4];
    const float* W1 = (const float*)d_in[6];
    const float* b1 = (const float*)d_in[7];
    const float* W2 = (const float*)d_in[8];
    const float* b2 = (const float*)d_in[9];
    float* out = (float*)d_out;

    // workspace layout
    int*   nidx = (int*)d_ws;                                   // 768 KB
    float* nw   = (float*)d_ws + NROWS * 3;                     // 768 KB
    unsigned short* h   = (unsigned short*)((float*)d_ws + 2 * NROWS * 3); // 32 MB bf16
    unsigned short* W1t = h + (size_t)NROWS * CHID;             // 192 KB
    unsigned short* W2t = W1t + 256 * K1;                       // 128 KB

    knn_kernel<<<BB * (NDST / 256), 256, 0, stream>>>(pos, pos_skip, nidx, nw);
    wt_kernel<<<(256 * K1 + 255) / 256, 256, 0, stream>>>(W1, W2, W1t, W2t);

    mfma_gemm_kernel<K1, true><<<(NROWS / 128) * 2, 256, 0, stream>>>(
        x, x_skip, nullptr, nidx, nw, W1t, b1, h, nullptr);

    mfma_gemm_kernel<K2, false><<<(NROWS / 128) * 2, 256, 0, stream>>>(
        nullptr, nullptr, h, nullptr, nullptr, W2t, b2, nullptr, out);

    const int tail = out_size - NROWS * CHID - NROWS * 3;
    if (tail >= 0) {
        tail_kernel<<<(NROWS * 3 + 255) / 256, 256, 0, stream>>>(pos_skip, out, tail);
    }
}

// Round 11
// 215.424 us; speedup vs baseline: 1.5434x; 1.5434x over previous
//
#include <hip/hip_runtime.h>
#include <math.h>

// Problem constants (match reference)
#define BB    16
#define NSRC  1024
#define NDST  4096
#define CIN   256
#define CSKIP 128
#define CHID  256
#define NROWS (BB * NDST)   // 65536 output rows
#define K1    (CIN + CSKIP) // 384
#define K2    CHID          // 256

typedef __attribute__((ext_vector_type(8))) short bf16x8;   // 8 bf16 (4 VGPRs)
typedef __attribute__((ext_vector_type(4))) float f32x4;    // MFMA accum

// round-to-nearest-even f32 -> bf16
__device__ inline unsigned short f2bf(float f) {
    union { float f; unsigned u; } v; v.f = f;
    unsigned r = v.u + 0x7FFFu + ((v.u >> 16) & 1u);
    return (unsigned short)(r >> 16);
}

// Exact merge of two sorted (d,idx) triples -> top-3, lex order (d, then idx).
// Matches jax.lax.top_k tie semantics (stable: lowest index wins ties).
__device__ inline void merge3(float& a0, int& x0, float& a1, int& x1, float& a2, int& x2,
                              float b0, int y0, float b1, int y1, float b2, int y2)
{
    const bool t0 = (a0 < b0) || (a0 == b0 && x0 < y0);
    const float r0 = t0 ? a0 : b0; const int s0 = t0 ? x0 : y0;
    const float A0 = t0 ? a1 : a0; const int X0 = t0 ? x1 : x0;
    const float A1 = t0 ? a2 : a1; const int X1 = t0 ? x2 : x1;
    const float B0 = t0 ? b0 : b1; const int Y0 = t0 ? y0 : y1;
    const float B1 = t0 ? b1 : b2; const int Y1 = t0 ? y1 : y2;
    const bool t1 = (A0 < B0) || (A0 == B0 && X0 < Y0);
    const float r1 = t1 ? A0 : B0; const int s1 = t1 ? X0 : Y0;
    const float A0b = t1 ? A1 : A0; const int X0b = t1 ? X1 : X0;
    const float B0b = t1 ? B0 : B1; const int Y0b = t1 ? Y0 : Y1;
    const bool t2 = (A0b < B0b) || (A0b == B0b && X0b < Y0b);
    a0 = r0; x0 = s0;
    a1 = r1; x1 = s1;
    a2 = t2 ? A0b : B0b; x2 = t2 ? X0b : Y0b;
}

// ---------------------------------------------------------------------------
// Kernel 1: 3-NN. R8/R9 diagnosis: 1 block/CU (occ 11%) -> latency-bound.
// Fix: 4 threads per dst point (each scans a 256-pt stride-4 subset, single
// chain), grid 1024 blocks -> 4 blocks/CU; exact shfl_xor lex merge.
// ---------------------------------------------------------------------------
__global__ __launch_bounds__(256) void knn_kernel(
    const float* __restrict__ pos,       // [BB*NSRC, 3]
    const float* __restrict__ pos_skip,  // [BB*NDST, 3]
    int*   __restrict__ nidx,            // [BB*NDST, 3]
    float* __restrict__ nw)              // [BB*NDST, 3]
{
    __shared__ float4 sp[NSRC];          // 16 KB
    const int bpc = NDST / 64;           // 64 blocks per cloud (64 pts/block)
    const int b   = blockIdx.x / bpc;
    const int r0  = (blockIdx.x % bpc) * 64;
    const int tid = threadIdx.x;

    const float* ps = pos + (size_t)b * NSRC * 3;
    for (int i = tid; i < NSRC; i += 256)
        sp[i] = make_float4(ps[i * 3 + 0], ps[i * 3 + 1], ps[i * 3 + 2], 0.f);
    __syncthreads();

    const int pt = tid >> 2;             // dst point within block (0..63)
    const int c  = tid & 3;              // src subset (j % 4 == c)
    const int dr = b * NDST + r0 + pt;
    const float qx = pos_skip[dr * 3 + 0];
    const float qy = pos_skip[dr * 3 + 1];
    const float qz = pos_skip[dr * 3 + 2];

    float d0 = 3.4e38f, d1 = 3.4e38f, d2 = 3.4e38f;
    int   i0 = 0x7fffffff, i1 = 0x7fffffff, i2 = 0x7fffffff;

    for (int j = c; j < NSRC; j += 16) { // 64 iters, 4 pts each (batched LDS reads)
        const float4 p0 = sp[j];
        const float4 p1 = sp[j + 4];
        const float4 p2 = sp[j + 8];
        const float4 p3 = sp[j + 12];
        float dd[4];
        {
            float dx, dy, dz;
            dx = qx - p0.x; dy = qy - p0.y; dz = qz - p0.z; dd[0] = dx*dx + dy*dy + dz*dz;
            dx = qx - p1.x; dy = qy - p1.y; dz = qz - p1.z; dd[1] = dx*dx + dy*dy + dz*dz;
            dx = qx - p2.x; dy = qy - p2.y; dz = qz - p2.z; dd[2] = dx*dx + dy*dy + dz*dz;
            dx = qx - p3.x; dy = qy - p3.y; dz = qz - p3.z; dd[3] = dx*dx + dy*dy + dz*dz;
        }
#pragma unroll
        for (int u = 0; u < 4; ++u) {
            const float d = dd[u];
            const int   ji = j + u * 4;
            if (d < d2) {                // strict <: earliest index wins in-subset
                if (d < d0)      { d2 = d1; i2 = i1; d1 = d0; i1 = i0; d0 = d; i0 = ji; }
                else if (d < d1) { d2 = d1; i2 = i1; d1 = d; i1 = ji; }
                else             { d2 = d; i2 = ji; }
            }
        }
    }

    // butterfly merge across the 4 subset-threads (lex-exact)
#pragma unroll
    for (int m = 1; m <= 2; m <<= 1) {
        const float e0 = __shfl_xor(d0, m), e1 = __shfl_xor(d1, m), e2 = __shfl_xor(d2, m);
        const int   y0 = __shfl_xor(i0, m), y1 = __shfl_xor(i1, m), y2 = __shfl_xor(i2, m);
        merge3(d0, i0, d1, i1, d2, i2, e0, y0, e1, y1, e2, y2);
    }

    if (c == 0) {
        const float w0 = 1.0f / (d0 + 1e-16f);
        const float w1 = 1.0f / (d1 + 1e-16f);
        const float w2 = 1.0f / (d2 + 1e-16f);
        const float inv = 1.0f / (w0 + w1 + w2);
        nidx[dr * 3 + 0] = b * NSRC + i0;
        nidx[dr * 3 + 1] = b * NSRC + i1;
        nidx[dr * 3 + 2] = b * NSRC + i2;
        nw[dr * 3 + 0] = w0 * inv;
        nw[dr * 3 + 1] = w1 * inv;
        nw[dr * 3 + 2] = w2 * inv;
    }
}

// ---------------------------------------------------------------------------
// Kernel 2: one-shot W transpose + bf16 cast: Wt[n][k] = bf16(W[k][n]).
// ---------------------------------------------------------------------------
__global__ __launch_bounds__(256) void wt_kernel(
    const float* __restrict__ W1, const float* __restrict__ W2,
    unsigned short* __restrict__ W1t, unsigned short* __restrict__ W2t)
{
    const int id = blockIdx.x * 256 + threadIdx.x;
    if (id < 256 * K1) {
        const int n = id / K1, k = id % K1;
        W1t[id] = f2bf(W1[(size_t)k * 256 + n]);
    }
    if (id < 256 * K2) {
        const int n = id / K2, k = id % K2;
        W2t[id] = f2bf(W2[(size_t)k * 256 + n]);
    }
}

// ---------------------------------------------------------------------------
// Kernel 3/4: bf16 MFMA GEMM, BM=64, BN=256 (full N), BK=32, 256 thr, 4 waves.
// WHOLE A panel staged to LDS up front (one batched gather window, interp
// fused for FIRST); K-loop reads LDS only + stages the L2-hot W tile.
// Wave w: rows 0..63 x cols w*64..w*64+63 (4x4 16x16x32 frags, fp32 acc).
// LDS: FIRST 69KB -> 2 blk/CU; !FIRST 53KB -> 3 blk/CU.
// ---------------------------------------------------------------------------
template <int KDIM, bool FIRST>
__global__ __launch_bounds__(256) void mfma_gemm_kernel(
    const float* __restrict__ x,             // FIRST
    const float* __restrict__ x_skip,        // FIRST
    const unsigned short* __restrict__ hin,  // !FIRST
    const int*   __restrict__ nidx,          // FIRST
    const float* __restrict__ nw,            // FIRST
    const unsigned short* __restrict__ Wt,   // [256][KDIM] bf16 (B^T)
    const float* __restrict__ bias,          // [256]
    unsigned short* __restrict__ hout,       // FIRST
    float* __restrict__ fout)                // !FIRST
{
    constexpr int BM = 64, BN = 256, BK = 32;
    constexpr int APAD = KDIM + 8;
    __shared__ __align__(16) unsigned short Af[BM][APAD];   // full A panel
    __shared__ __align__(16) unsigned short Bt[BN][40];     // one B K-tile

    const int tid     = threadIdx.x;
    const int rowBase = blockIdx.x * BM;

    // ---- stage ENTIRE A panel (64 x KDIM) ----
    const int ra = tid >> 2;               // row 0..63
    const int cq = tid & 3;                // column-group lane
    if (FIRST) {
        const float4* x4  = (const float4*)x;
        const float4* xs4 = (const float4*)x_skip;
        const size_t g = (size_t)(rowBase + ra) * 3;
        const int   gi0 = nidx[g + 0], gi1 = nidx[g + 1], gi2 = nidx[g + 2];
        const float gw0 = nw[g + 0],   gw1 = nw[g + 1],   gw2 = nw[g + 2];
#pragma unroll
        for (int cc = 0; cc < 24; ++cc) {  // 24 float4 groups/thread (96 cols)
            const int f4i = cq + cc * 4;   // 0..95
            unsigned short o[4];
            if (cc < 16) {                 // interp region (cols 0..255), uniform branch
                const float4 f0 = x4[(size_t)gi0 * (CIN / 4) + f4i];
                const float4 f1 = x4[(size_t)gi1 * (CIN / 4) + f4i];
                const float4 f2 = x4[(size_t)gi2 * (CIN / 4) + f4i];
                o[0] = f2bf(gw0 * f0.x + gw1 * f1.x + gw2 * f2.x);
                o[1] = f2bf(gw0 * f0.y + gw1 * f1.y + gw2 * f2.y);
                o[2] = f2bf(gw0 * f0.z + gw1 * f1.z + gw2 * f2.z);
                o[3] = f2bf(gw0 * f0.w + gw1 * f1.w + gw2 * f2.w);
            } else {                       // x_skip region (cols 256..383)
                const float4 f = xs4[(size_t)(rowBase + ra) * (CSKIP / 4) + (f4i - 64)];
                o[0] = f2bf(f.x); o[1] = f2bf(f.y); o[2] = f2bf(f.z); o[3] = f2bf(f.w);
            }
            *(ushort4*)&Af[ra][f4i * 4] = *(ushort4*)o;
        }
    } else {
        const unsigned short* hp = hin + (size_t)(rowBase + ra) * K2;
#pragma unroll
        for (int cc = 0; cc < 8; ++cc) {   // 8 bf16x8 groups/thread
            const int f8i = cq + cc * 4;   // 0..31
            *(bf16x8*)&Af[ra][f8i * 8] = *(const bf16x8*)&hp[f8i * 8];
        }
    }

    f32x4 acc[4][4];
#pragma unroll
    for (int i = 0; i < 4; ++i)
#pragma unroll
        for (int j = 0; j < 4; ++j) acc[i][j] = (f32x4){0.f, 0.f, 0.f, 0.f};

    const int l  = tid & 63;
    const int w  = tid >> 6;               // wave 0..3 -> cols w*64..
    const int cl = l & 15;
    const int k0 = (l >> 4) * 8;
    const int rg = (l >> 4) * 4;

    const int rb = tid >> 1;               // B staging rows rb, rb+128
    const int kh = (tid & 1) * 16;

    for (int kt = 0; kt < KDIM; kt += BK) {
        // stage B K-tile into regs (L2-hot Wt)
        const unsigned short* wp0 = &Wt[(size_t)rb * KDIM + kt + kh];
        const unsigned short* wp1 = &Wt[(size_t)(rb + 128) * KDIM + kt + kh];
        const bf16x8 b0 = *(const bf16x8*)&wp0[0];
        const bf16x8 b1 = *(const bf16x8*)&wp0[8];
        const bf16x8 b2 = *(const bf16x8*)&wp1[0];
        const bf16x8 b3 = *(const bf16x8*)&wp1[8];
        __syncthreads();                   // prev step's Bt reads done (iter0: Af ready)
        *(bf16x8*)&Bt[rb][kh]           = b0;
        *(bf16x8*)&Bt[rb][kh + 8]       = b1;
        *(bf16x8*)&Bt[rb + 128][kh]     = b2;
        *(bf16x8*)&Bt[rb + 128][kh + 8] = b3;
        __syncthreads();                   // Bt ready

        bf16x8 af[4], bfr[4];
#pragma unroll
        for (int mt = 0; mt < 4; ++mt)
            af[mt] = *(const bf16x8*)&Af[mt * 16 + cl][kt + k0];
#pragma unroll
        for (int nt = 0; nt < 4; ++nt)
            bfr[nt] = *(const bf16x8*)&Bt[w * 64 + nt * 16 + cl][k0];
#pragma unroll
        for (int mt = 0; mt < 4; ++mt)
#pragma unroll
            for (int nt = 0; nt < 4; ++nt)
                acc[mt][nt] = __builtin_amdgcn_mfma_f32_16x16x32_bf16(
                    af[mt], bfr[nt], acc[mt][nt], 0, 0, 0);
    }

    // ---- epilogue: D layout col = l&15, row = (l>>4)*4 + reg [m89] ----
#pragma unroll
    for (int nt = 0; nt < 4; ++nt) {
        const int col = w * 64 + nt * 16 + cl;
        const float bv = bias[col];
#pragma unroll
        for (int mt = 0; mt < 4; ++mt) {
            const int row = rowBase + mt * 16 + rg;
#pragma unroll
            for (int rr = 0; rr < 4; ++rr) {
                float v = acc[mt][nt][rr] + bv;
                if (FIRST) {
                    v = fmaxf(v, 0.f);
                    hout[(size_t)(row + rr) * CHID + col] = f2bf(v);
                } else {
                    fout[(size_t)(row + rr) * CHID + col] = v;
                }
            }
        }
    }
}

// ---------------------------------------------------------------------------
// Kernel 5: tuple tail (guarded by out_size).
// ---------------------------------------------------------------------------
__global__ __launch_bounds__(256) void tail_kernel(
    const float* __restrict__ pos_skip, float* __restrict__ out, int tailElems)
{
    const int i  = blockIdx.x * blockDim.x + threadIdx.x;
    const int PS = NROWS * 3;
    float* o1 = out + (size_t)NROWS * CHID;
    if (i < PS) o1[i] = pos_skip[i];
    if (i < NROWS) {
        const int bval = i >> 12;          // i / NDST
        if (tailElems == NROWS) {
            o1[PS + i] = (float)bval;
        } else if (tailElems == 2 * NROWS) {
            ((long long*)(o1 + PS))[i] = (long long)bval;
        }
    }
}

// ---------------------------------------------------------------------------
extern "C" void kernel_launch(void* const* d_in, const int* in_sizes, int n_in,
                              void* d_out, int out_size, void* d_ws, size_t ws_size,
                              hipStream_t stream)
{
    const float* x        = (const float*)d_in[0];
    const float* pos      = (const float*)d_in[1];
    const float* x_skip   = (const float*)d_in[3];
    const float* pos_skip = (const float*)d_in[4];
    const float* W1 = (const float*)d_in[6];
    const float* b1 = (const float*)d_in[7];
    const float* W2 = (const float*)d_in[8];
    const float* b2 = (const float*)d_in[9];
    float* out = (float*)d_out;

    // workspace layout
    int*   nidx = (int*)d_ws;                                   // 768 KB
    float* nw   = (float*)d_ws + NROWS * 3;                     // 768 KB
    unsigned short* h   = (unsigned short*)((float*)d_ws + 2 * NROWS * 3); // 32 MB bf16
    unsigned short* W1t = h + (size_t)NROWS * CHID;             // 192 KB
    unsigned short* W2t = W1t + 256 * K1;                       // 128 KB

    knn_kernel<<<BB * (NDST / 64), 256, 0, stream>>>(pos, pos_skip, nidx, nw);
    wt_kernel<<<(256 * K1 + 255) / 256, 256, 0, stream>>>(W1, W2, W1t, W2t);

    mfma_gemm_kernel<K1, true><<<NROWS / 64, 256, 0, stream>>>(
        x, x_skip, nullptr, nidx, nw, W1t, b1, h, nullptr);

    mfma_gemm_kernel<K2, false><<<NROWS / 64, 256, 0, stream>>>(
        nullptr, nullptr, h, nullptr, nullptr, W2t, b2, nullptr, out);

    const int tail = out_size - NROWS * CHID - NROWS * 3;
    if (tail >= 0) {
        tail_kernel<<<(NROWS * 3 + 255) / 256, 256, 0, stream>>>(pos_skip, out, tail);
    }
}